// Round 1
// baseline (745.395 us; speedup 1.0000x reference)
//
#include <hip/hip_runtime.h>
#include <hip/hip_bf16.h>

#define LSPANS 4096
#define BB 32
#define HH 1024
#define DD 1024
#define VV 32000
#define K1 2048   // 2H
#define NT2 250   // V / 128

typedef unsigned short u16;
typedef __attribute__((ext_vector_type(8))) short bf16x8v;
typedef __attribute__((ext_vector_type(4))) float f32x4v;

__device__ __forceinline__ u16 f2bf(float x) {
  union { float f; unsigned u; } v; v.f = x;
  unsigned r = (v.u >> 16) & 1u;
  return (u16)((v.u + 0x7fffu + r) >> 16);
}

// ---------------- fp32 -> bf16 bulk convert (vector x4) ----------------
__global__ void cvt_kernel(const float* __restrict__ in, u16* __restrict__ out, int n4) {
  int i = blockIdx.x * blockDim.x + threadIdx.x;
  int stride = gridDim.x * blockDim.x;
  for (; i < n4; i += stride) {
    float4 v = ((const float4*)in)[i];
    ushort4 o;
    o.x = f2bf(v.x); o.y = f2bf(v.y); o.z = f2bf(v.z); o.w = f2bf(v.w);
    ((ushort4*)out)[i] = o;
  }
}

// ---------------- gather span endpoints -> bf16 [L, 2H] ----------------
__global__ void gather_kernel(const float* __restrict__ hidden,
                              const int* __restrict__ bid,
                              const int* __restrict__ sb,
                              const int* __restrict__ se,
                              u16* __restrict__ out) {
  int l = blockIdx.x;
  int t = threadIdx.x;  // 256 threads, 4 floats each per half
  int b  = bid[l];
  const float* p0 = hidden + ((size_t)sb[l] * BB + b) * HH;
  const float* p1 = hidden + ((size_t)se[l] * BB + b) * HH;
  u16* dst = out + (size_t)l * K1;
  float4 v0 = ((const float4*)p0)[t];
  float4 v1 = ((const float4*)p1)[t];
  ushort4 o0; o0.x = f2bf(v0.x); o0.y = f2bf(v0.y); o0.z = f2bf(v0.z); o0.w = f2bf(v0.w);
  ushort4 o1; o1.x = f2bf(v1.x); o1.y = f2bf(v1.y); o1.z = f2bf(v1.z); o1.w = f2bf(v1.w);
  ((ushort4*)dst)[t]          = o0;
  ((ushort4*)(dst + HH))[t]   = o1;
}

// ---------------- 128x128 MFMA GEMM (NT: A[M,K], B[N,K], both K-contig) ----
// EPI=1: out = tanh(acc + bias) -> bf16 feat.  EPI=2: fused softmax partials.
template <int K_, int EPI>
__launch_bounds__(256, 2)
__global__ void gemm_kernel(const u16* __restrict__ A, const u16* __restrict__ B,
                            int Ntot,
                            const float* __restrict__ bias, u16* __restrict__ feat_out,
                            const int* __restrict__ tags,
                            float* __restrict__ pmax, float* __restrict__ psum,
                            float* __restrict__ ltag) {
  __shared__ __align__(16) u16 As[128 * 64];
  __shared__ __align__(16) u16 Bs[128 * 64];
  __shared__ float rmax[2][128];
  __shared__ float rsum[2][128];
  __shared__ int   stags[128];

  const int tid  = threadIdx.x;
  const int lane = tid & 63;
  const int w    = tid >> 6;       // wave 0..3
  const int wm   = w & 1;          // wave row (M)
  const int wn   = w >> 1;         // wave col (N)
  const int q    = lane >> 4;      // quad 0..3
  const int lm   = lane & 15;
  const int mBase = blockIdx.x * 128;
  const int nBase = blockIdx.y * 128;

  if (EPI == 2 && tid < 128) stags[tid] = tags[mBase + tid];

  f32x4v acc[4][4];
#pragma unroll
  for (int i = 0; i < 4; ++i)
#pragma unroll
    for (int j = 0; j < 4; ++j) acc[i][j] = (f32x4v){0.f, 0.f, 0.f, 0.f};

  // staging: each wave fills 32 rows (4 issues of 8 rows); lane i -> ldsbase + i*16B
  const int srow = w * 32 + (lane >> 3);
  const int scol = (lane & 7) * 8;
  const u16* Ag = A + (size_t)(mBase + srow) * K_ + scol;
  const u16* Bg = B + (size_t)(nBase + srow) * K_ + scol;

  for (int k0 = 0; k0 < K_; k0 += 64) {
#pragma unroll
    for (int c = 0; c < 4; ++c) {
      __builtin_amdgcn_global_load_lds(
          (const __attribute__((address_space(1))) void*)(Ag + k0 + (size_t)c * 8 * K_),
          (__attribute__((address_space(3))) void*)(As + (w * 32 + c * 8) * 64), 16, 0, 0);
    }
#pragma unroll
    for (int c = 0; c < 4; ++c) {
      __builtin_amdgcn_global_load_lds(
          (const __attribute__((address_space(1))) void*)(Bg + k0 + (size_t)c * 8 * K_),
          (__attribute__((address_space(3))) void*)(Bs + (w * 32 + c * 8) * 64), 16, 0, 0);
    }
    __syncthreads();
#pragma unroll
    for (int kk = 0; kk < 64; kk += 32) {
      bf16x8v af[4], bfr[4];
#pragma unroll
      for (int i = 0; i < 4; ++i)
        af[i] = *(const bf16x8v*)(As + (wm * 64 + i * 16 + lm) * 64 + kk + q * 8);
#pragma unroll
      for (int j = 0; j < 4; ++j)
        bfr[j] = *(const bf16x8v*)(Bs + (wn * 64 + j * 16 + lm) * 64 + kk + q * 8);
#pragma unroll
      for (int i = 0; i < 4; ++i)
#pragma unroll
        for (int j = 0; j < 4; ++j)
          acc[i][j] = __builtin_amdgcn_mfma_f32_16x16x32_bf16(af[i], bfr[j], acc[i][j], 0, 0, 0);
    }
    __syncthreads();
  }

  // C/D layout: col = lane&15, row = quad*4 + reg
  if constexpr (EPI == 1) {
    float bj[4];
#pragma unroll
    for (int j = 0; j < 4; ++j) bj[j] = bias[nBase + wn * 64 + j * 16 + lm];
#pragma unroll
    for (int i = 0; i < 4; ++i)
#pragma unroll
      for (int j = 0; j < 4; ++j)
#pragma unroll
        for (int r = 0; r < 4; ++r) {
          int tr = wm * 64 + i * 16 + q * 4 + r;
          int tc = wn * 64 + j * 16 + lm;
          float v = tanhf(acc[i][j][r] + bj[j]);
          feat_out[(size_t)(mBase + tr) * Ntot + nBase + tc] = f2bf(v);
        }
  }

  if constexpr (EPI == 2) {
    // phase 1: per-row max over this wave's 64 cols -> LDS
#pragma unroll
    for (int i = 0; i < 4; ++i)
#pragma unroll
      for (int r = 0; r < 4; ++r) {
        float m = fmaxf(fmaxf(acc[i][0][r], acc[i][1][r]),
                        fmaxf(acc[i][2][r], acc[i][3][r]));
#pragma unroll
        for (int off = 1; off < 16; off <<= 1) m = fmaxf(m, __shfl_xor(m, off, 64));
        if (lm == 0) rmax[wn][wm * 64 + i * 16 + q * 4 + r] = m;
      }
    __syncthreads();
    // phase 2: sumexp against the full 128-col row max
#pragma unroll
    for (int i = 0; i < 4; ++i)
#pragma unroll
      for (int r = 0; r < 4; ++r) {
        int tr = wm * 64 + i * 16 + q * 4 + r;
        float M = fmaxf(rmax[0][tr], rmax[1][tr]);
        float s = __expf(acc[i][0][r] - M) + __expf(acc[i][1][r] - M) +
                  __expf(acc[i][2][r] - M) + __expf(acc[i][3][r] - M);
#pragma unroll
        for (int off = 1; off < 16; off <<= 1) s += __shfl_xor(s, off, 64);
        if (lm == 0) rsum[wn][tr] = s;
      }
    __syncthreads();
    if (tid < 128) {
      float M = fmaxf(rmax[0][tid], rmax[1][tid]);
      float S = rsum[0][tid] + rsum[1][tid];
      pmax[(size_t)blockIdx.y * LSPANS + mBase + tid] = M;
      psum[(size_t)blockIdx.y * LSPANS + mBase + tid] = S;
    }
    // tag logit capture (exactly one matching column per row globally)
#pragma unroll
    for (int i = 0; i < 4; ++i)
#pragma unroll
      for (int r = 0; r < 4; ++r) {
        int tr = wm * 64 + i * 16 + q * 4 + r;
        int tg = stags[tr];
#pragma unroll
        for (int j = 0; j < 4; ++j) {
          int gc = nBase + wn * 64 + j * 16 + lm;
          if (tg == gc) ltag[mBase + tr] = acc[i][j][r];
        }
      }
  }
}

// ---------------- merge partials, weighted-mean NLL ----------------
__global__ void finalize_kernel(const float* __restrict__ pmax, const float* __restrict__ psum,
                                const float* __restrict__ ltag, const int* __restrict__ tags,
                                const float* __restrict__ dprob, float* __restrict__ out) {
  int l = blockIdx.x * blockDim.x + threadIdx.x;  // 16 x 256 = 4096
  const float* pm = pmax + l;
  const float* ps = psum + l;
  float M = -1e30f;
  for (int t = 0; t < NT2; ++t) M = fmaxf(M, pm[(size_t)t * LSPANS]);
  float S = 0.f;
  for (int t = 0; t < NT2; ++t) S += ps[(size_t)t * LSPANS] * __expf(pm[(size_t)t * LSPANS] - M);
  float nll = M + logf(S) - ltag[l];
  float wgt = 1.0f - dprob[tags[l]];
  float val = nll * wgt * (1.0f / (4096.0f + 1e-5f));
  // block reduce
  __shared__ float red[4];
#pragma unroll
  for (int off = 32; off; off >>= 1) val += __shfl_down(val, off, 64);
  if ((threadIdx.x & 63) == 0) red[threadIdx.x >> 6] = val;
  __syncthreads();
  if (threadIdx.x == 0) atomicAdd(out, red[0] + red[1] + red[2] + red[3]);
}

extern "C" void kernel_launch(void* const* d_in, const int* in_sizes, int n_in,
                              void* d_out, int out_size, void* d_ws, size_t ws_size,
                              hipStream_t stream) {
  const float* hidden = (const float*)d_in[0];
  const float* W1     = (const float*)d_in[1];
  const float* b1     = (const float*)d_in[2];
  const float* Wout   = (const float*)d_in[3];
  const float* dprob  = (const float*)d_in[4];
  const int*   bid    = (const int*)d_in[5];
  const int*   sb     = (const int*)d_in[6];
  const int*   se     = (const int*)d_in[7];
  const int*   tags   = (const int*)d_in[8];
  float* out = (float*)d_out;

  char* ws = (char*)d_ws;
  u16* A1    = (u16*)ws;                 ws += (size_t)LSPANS * K1 * 2;      // 16.78 MB
  u16* W1b   = (u16*)ws;                 ws += (size_t)DD * K1 * 2;          //  4.19 MB
  u16* Woutb = (u16*)ws;                 ws += (size_t)VV * DD * 2;          // 65.54 MB
  u16* feat  = (u16*)ws;                 ws += (size_t)LSPANS * DD * 2;      //  8.39 MB
  float* pmax = (float*)ws;              ws += (size_t)NT2 * LSPANS * 4;     //  4.10 MB
  float* psum = (float*)ws;              ws += (size_t)NT2 * LSPANS * 4;     //  4.10 MB
  float* ltag = (float*)ws;              ws += (size_t)LSPANS * 4;

  hipMemsetAsync(d_out, 0, sizeof(float), stream);

  // bf16 conversions
  {
    int n4 = DD * K1 / 4;
    cvt_kernel<<<(n4 + 255) / 256, 256, 0, stream>>>(W1, W1b, n4);
  }
  {
    int n4 = VV * DD / 4;
    cvt_kernel<<<(n4 + 255) / 256, 256, 0, stream>>>(Wout, Woutb, n4);
  }
  // gather span endpoint embeddings
  gather_kernel<<<LSPANS, 256, 0, stream>>>(hidden, bid, sb, se, A1);

  // GEMM1: feat = tanh(A1 @ W1^T + b1)   [4096 x 1024]
  gemm_kernel<K1, 1><<<dim3(LSPANS / 128, DD / 128), 256, 0, stream>>>(
      A1, W1b, DD, b1, feat, nullptr, nullptr, nullptr, nullptr);

  // GEMM2: logits tiles + fused softmax partials   [4096 x 32000]
  gemm_kernel<DD, 2><<<dim3(LSPANS / 128, NT2), 256, 0, stream>>>(
      feat, Woutb, VV, nullptr, nullptr, tags, pmax, psum, ltag);

  // merge + weighted mean
  finalize_kernel<<<LSPANS / 256, 256, 0, stream>>>(pmax, psum, ltag, tags, dprob, out);
}

// Round 2
// 652.986 us; speedup vs baseline: 1.1415x; 1.1415x over previous
//
#include <hip/hip_runtime.h>
#include <hip/hip_bf16.h>

#define LSPANS 4096
#define BB 32
#define HH 1024
#define DD 1024
#define VV 32000
#define K1 2048   // 2H
#define NT2 250   // V / 128

typedef unsigned short u16;
typedef __attribute__((ext_vector_type(8))) short bf16x8v;
typedef __attribute__((ext_vector_type(4))) float f32x4v;

__device__ __forceinline__ u16 f2bf(float x) {
  union { float f; unsigned u; } v; v.f = x;
  unsigned r = (v.u >> 16) & 1u;
  return (u16)((v.u + 0x7fffu + r) >> 16);
}

// ---------------- fp32 -> bf16 bulk convert (vector x4) ----------------
__global__ void cvt_kernel(const float* __restrict__ in, u16* __restrict__ out, int n4) {
  int i = blockIdx.x * blockDim.x + threadIdx.x;
  int stride = gridDim.x * blockDim.x;
  for (; i < n4; i += stride) {
    float4 v = ((const float4*)in)[i];
    ushort4 o;
    o.x = f2bf(v.x); o.y = f2bf(v.y); o.z = f2bf(v.z); o.w = f2bf(v.w);
    ((ushort4*)out)[i] = o;
  }
}

// ---------------- gather span endpoints -> bf16 [L, 2H] ----------------
__global__ void gather_kernel(const float* __restrict__ hidden,
                              const int* __restrict__ bid,
                              const int* __restrict__ sb,
                              const int* __restrict__ se,
                              u16* __restrict__ out) {
  int l = blockIdx.x;
  int t = threadIdx.x;  // 256 threads, 4 floats each per half
  int b  = bid[l];
  const float* p0 = hidden + ((size_t)sb[l] * BB + b) * HH;
  const float* p1 = hidden + ((size_t)se[l] * BB + b) * HH;
  u16* dst = out + (size_t)l * K1;
  float4 v0 = ((const float4*)p0)[t];
  float4 v1 = ((const float4*)p1)[t];
  ushort4 o0; o0.x = f2bf(v0.x); o0.y = f2bf(v0.y); o0.z = f2bf(v0.z); o0.w = f2bf(v0.w);
  ushort4 o1; o1.x = f2bf(v1.x); o1.y = f2bf(v1.y); o1.z = f2bf(v1.z); o1.w = f2bf(v1.w);
  ((ushort4*)dst)[t]          = o0;
  ((ushort4*)(dst + HH))[t]   = o1;
}

// ---------------- 128x128 MFMA GEMM (NT: A[M,K], B[N,K], both K-contig) ----
// LDS layout is XOR-swizzled: LDS[r][chunk c] holds global chunk (c ^ (r&7)),
// chunks are 8 u16 = 16 B. global_load_lds forces lane i -> LDS offset i*16B,
// so the swizzle is applied on the global SOURCE address (per-lane column
// permutation within the 128B row segment). Fragment reads use
// chunk = kch ^ (row&7); row&7 = lm&7 spans 0..7 across the 16 fragment
// lanes -> banks fully spread (only free 2-way aliasing).
// EPI=1: out = tanh(acc + bias) -> bf16 feat.  EPI=2: fused softmax partials.
template <int K_, int EPI>
__launch_bounds__(256, 2)
__global__ void gemm_kernel(const u16* __restrict__ A, const u16* __restrict__ B,
                            int Ntot,
                            const float* __restrict__ bias, u16* __restrict__ feat_out,
                            const int* __restrict__ tags,
                            float* __restrict__ pmax, float* __restrict__ psum,
                            float* __restrict__ ltag) {
  __shared__ __align__(16) u16 As[128 * 64];
  __shared__ __align__(16) u16 Bs[128 * 64];
  __shared__ float rmax[2][128];
  __shared__ float rsum[2][128];
  __shared__ int   stags[128];

  const int tid  = threadIdx.x;
  const int lane = tid & 63;
  const int w    = tid >> 6;       // wave 0..3
  const int wm   = w & 1;          // wave row (M)
  const int wn   = w >> 1;         // wave col (N)
  const int q    = lane >> 4;      // quad 0..3
  const int lm   = lane & 15;
  const int mBase = blockIdx.x * 128;
  const int nBase = blockIdx.y * 128;

  if (EPI == 2 && tid < 128) stags[tid] = tags[mBase + tid];

  f32x4v acc[4][4];
#pragma unroll
  for (int i = 0; i < 4; ++i)
#pragma unroll
    for (int j = 0; j < 4; ++j) acc[i][j] = (f32x4v){0.f, 0.f, 0.f, 0.f};

  // staging: each wave fills 32 rows (4 issues of 8 rows); lane i writes
  // LDS row (i>>3), LDS chunk (i&7); it must therefore FETCH global chunk
  // (i&7) ^ (i>>3) so that LDS[r][c] = G[r][c ^ (r&7)].
  const int srow = w * 32 + (lane >> 3);
  const int scol = ((lane & 7) ^ (lane >> 3)) * 8;   // swizzled source column
  const u16* Ag = A + (size_t)(mBase + srow) * K_ + scol;
  const u16* Bg = B + (size_t)(nBase + srow) * K_ + scol;

  for (int k0 = 0; k0 < K_; k0 += 64) {
#pragma unroll
    for (int c = 0; c < 4; ++c) {
      __builtin_amdgcn_global_load_lds(
          (const __attribute__((address_space(1))) void*)(Ag + k0 + (size_t)c * 8 * K_),
          (__attribute__((address_space(3))) void*)(As + (w * 32 + c * 8) * 64), 16, 0, 0);
    }
#pragma unroll
    for (int c = 0; c < 4; ++c) {
      __builtin_amdgcn_global_load_lds(
          (const __attribute__((address_space(1))) void*)(Bg + k0 + (size_t)c * 8 * K_),
          (__attribute__((address_space(3))) void*)(Bs + (w * 32 + c * 8) * 64), 16, 0, 0);
    }
    __syncthreads();
#pragma unroll
    for (int kk = 0; kk < 64; kk += 32) {
      bf16x8v af[4], bfr[4];
      const int sw = lm & 7;                 // row&7 for this lane's frag rows
#pragma unroll
      for (int i = 0; i < 4; ++i) {
        int row = wm * 64 + i * 16 + lm;
        int kch = (kk >> 3) + q;             // wanted global chunk index
        af[i] = *(const bf16x8v*)(As + row * 64 + ((kch ^ sw) << 3));
      }
#pragma unroll
      for (int j = 0; j < 4; ++j) {
        int row = wn * 64 + j * 16 + lm;
        int kch = (kk >> 3) + q;
        bfr[j] = *(const bf16x8v*)(Bs + row * 64 + ((kch ^ sw) << 3));
      }
#pragma unroll
      for (int i = 0; i < 4; ++i)
#pragma unroll
        for (int j = 0; j < 4; ++j)
          acc[i][j] = __builtin_amdgcn_mfma_f32_16x16x32_bf16(af[i], bfr[j], acc[i][j], 0, 0, 0);
    }
    __syncthreads();
  }

  // C/D layout: col = lane&15, row = quad*4 + reg
  if constexpr (EPI == 1) {
    float bj[4];
#pragma unroll
    for (int j = 0; j < 4; ++j) bj[j] = bias[nBase + wn * 64 + j * 16 + lm];
#pragma unroll
    for (int i = 0; i < 4; ++i)
#pragma unroll
      for (int j = 0; j < 4; ++j)
#pragma unroll
        for (int r = 0; r < 4; ++r) {
          int tr = wm * 64 + i * 16 + q * 4 + r;
          int tc = wn * 64 + j * 16 + lm;
          float v = tanhf(acc[i][j][r] + bj[j]);
          feat_out[(size_t)(mBase + tr) * Ntot + nBase + tc] = f2bf(v);
        }
  }

  if constexpr (EPI == 2) {
    // phase 1: per-row max over this wave's 64 cols -> LDS
#pragma unroll
    for (int i = 0; i < 4; ++i)
#pragma unroll
      for (int r = 0; r < 4; ++r) {
        float m = fmaxf(fmaxf(acc[i][0][r], acc[i][1][r]),
                        fmaxf(acc[i][2][r], acc[i][3][r]));
#pragma unroll
        for (int off = 1; off < 16; off <<= 1) m = fmaxf(m, __shfl_xor(m, off, 64));
        if (lm == 0) rmax[wn][wm * 64 + i * 16 + q * 4 + r] = m;
      }
    __syncthreads();
    // phase 2: sumexp against the full 128-col row max
#pragma unroll
    for (int i = 0; i < 4; ++i)
#pragma unroll
      for (int r = 0; r < 4; ++r) {
        int tr = wm * 64 + i * 16 + q * 4 + r;
        float M = fmaxf(rmax[0][tr], rmax[1][tr]);
        float s = __expf(acc[i][0][r] - M) + __expf(acc[i][1][r] - M) +
                  __expf(acc[i][2][r] - M) + __expf(acc[i][3][r] - M);
#pragma unroll
        for (int off = 1; off < 16; off <<= 1) s += __shfl_xor(s, off, 64);
        if (lm == 0) rsum[wn][tr] = s;
      }
    __syncthreads();
    if (tid < 128) {
      float M = fmaxf(rmax[0][tid], rmax[1][tid]);
      float S = rsum[0][tid] + rsum[1][tid];
      pmax[(size_t)blockIdx.y * LSPANS + mBase + tid] = M;
      psum[(size_t)blockIdx.y * LSPANS + mBase + tid] = S;
    }
    // tag logit capture (exactly one matching column per row globally)
#pragma unroll
    for (int i = 0; i < 4; ++i)
#pragma unroll
      for (int r = 0; r < 4; ++r) {
        int tr = wm * 64 + i * 16 + q * 4 + r;
        int tg = stags[tr];
#pragma unroll
        for (int j = 0; j < 4; ++j) {
          int gc = nBase + wn * 64 + j * 16 + lm;
          if (tg == gc) ltag[mBase + tr] = acc[i][j][r];
        }
      }
  }
}

// ---------------- merge partials, weighted-mean NLL ----------------
__global__ void finalize_kernel(const float* __restrict__ pmax, const float* __restrict__ psum,
                                const float* __restrict__ ltag, const int* __restrict__ tags,
                                const float* __restrict__ dprob, float* __restrict__ out) {
  int l = blockIdx.x * blockDim.x + threadIdx.x;  // 16 x 256 = 4096
  const float* pm = pmax + l;
  const float* ps = psum + l;
  float M = -1e30f;
  for (int t = 0; t < NT2; ++t) M = fmaxf(M, pm[(size_t)t * LSPANS]);
  float S = 0.f;
  for (int t = 0; t < NT2; ++t) S += ps[(size_t)t * LSPANS] * __expf(pm[(size_t)t * LSPANS] - M);
  float nll = M + logf(S) - ltag[l];
  float wgt = 1.0f - dprob[tags[l]];
  float val = nll * wgt * (1.0f / (4096.0f + 1e-5f));
  // block reduce
  __shared__ float red[4];
#pragma unroll
  for (int off = 32; off; off >>= 1) val += __shfl_down(val, off, 64);
  if ((threadIdx.x & 63) == 0) red[threadIdx.x >> 6] = val;
  __syncthreads();
  if (threadIdx.x == 0) atomicAdd(out, red[0] + red[1] + red[2] + red[3]);
}

extern "C" void kernel_launch(void* const* d_in, const int* in_sizes, int n_in,
                              void* d_out, int out_size, void* d_ws, size_t ws_size,
                              hipStream_t stream) {
  const float* hidden = (const float*)d_in[0];
  const float* W1     = (const float*)d_in[1];
  const float* b1     = (const float*)d_in[2];
  const float* Wout   = (const float*)d_in[3];
  const float* dprob  = (const float*)d_in[4];
  const int*   bid    = (const int*)d_in[5];
  const int*   sb     = (const int*)d_in[6];
  const int*   se     = (const int*)d_in[7];
  const int*   tags   = (const int*)d_in[8];
  float* out = (float*)d_out;

  char* ws = (char*)d_ws;
  u16* A1    = (u16*)ws;                 ws += (size_t)LSPANS * K1 * 2;      // 16.78 MB
  u16* W1b   = (u16*)ws;                 ws += (size_t)DD * K1 * 2;          //  4.19 MB
  u16* Woutb = (u16*)ws;                 ws += (size_t)VV * DD * 2;          // 65.54 MB
  u16* feat  = (u16*)ws;                 ws += (size_t)LSPANS * DD * 2;      //  8.39 MB
  float* pmax = (float*)ws;              ws += (size_t)NT2 * LSPANS * 4;     //  4.10 MB
  float* psum = (float*)ws;              ws += (size_t)NT2 * LSPANS * 4;     //  4.10 MB
  float* ltag = (float*)ws;              ws += (size_t)LSPANS * 4;

  hipMemsetAsync(d_out, 0, sizeof(float), stream);

  // bf16 conversions
  {
    int n4 = DD * K1 / 4;
    cvt_kernel<<<(n4 + 255) / 256, 256, 0, stream>>>(W1, W1b, n4);
  }
  {
    int n4 = VV * DD / 4;
    cvt_kernel<<<(n4 + 255) / 256, 256, 0, stream>>>(Wout, Woutb, n4);
  }
  // gather span endpoint embeddings
  gather_kernel<<<LSPANS, 256, 0, stream>>>(hidden, bid, sb, se, A1);

  // GEMM1: feat = tanh(A1 @ W1^T + b1)   [4096 x 1024]
  gemm_kernel<K1, 1><<<dim3(LSPANS / 128, DD / 128), 256, 0, stream>>>(
      A1, W1b, DD, b1, feat, nullptr, nullptr, nullptr, nullptr);

  // GEMM2: logits tiles + fused softmax partials   [4096 x 32000]
  gemm_kernel<DD, 2><<<dim3(LSPANS / 128, NT2), 256, 0, stream>>>(
      feat, Woutb, VV, nullptr, nullptr, tags, pmax, psum, ltag);

  // merge + weighted mean
  finalize_kernel<<<LSPANS / 256, 256, 0, stream>>>(pmax, psum, ltag, tags, dprob, out);
}